// Round 4
// baseline (224.400 us; speedup 1.0000x reference)
//
#include <hip/hip_runtime.h>

// SpatialAttention B=4 HW=4096 C=256 NH=4 d=64 — f16 MFMA flash attention.
// R9 = R5 loop structure (R8's pipelined interval reverted)
//      + R7/R8 prepass identities (bk, bv dropped exactly; wk folded into Qhat)
//      + QTILE 128 -> 64: grid 1024 blocks = 4 independent barrier groups/CU
//        (R5 was grid-limited at 2; R6 showed lockstep waves don't help, so
//        the lever is independent groups). Per-wave mix unchanged, work halved.
//      + XCD-locality swizzle: bh=(lin&7)*2+((lin>>3)&1) keeps each XCD's
//        K/V working set at 2MB (< 4MB L2) despite 2x staging traffic.

#define HW 4096
#define CCH 256
#define DH 64
#define NH 4
#define QTILE 64
#define KTILE 64
#define NKT (HW / KTILE)
#define LOG2E 1.44269504088896340736f

typedef __attribute__((ext_vector_type(8))) _Float16 half8;
typedef __attribute__((ext_vector_type(4))) _Float16 half4;
typedef __attribute__((ext_vector_type(2))) __fp16 pk16x2;   // cvt_pkrtz native type
typedef __attribute__((ext_vector_type(4))) float floatx4;

typedef __attribute__((address_space(1))) const unsigned int gbl_u32;
typedef __attribute__((address_space(3))) unsigned int lds_u32;

__device__ __forceinline__ void gload_lds16(const void* g, void* l) {
    __builtin_amdgcn_global_load_lds((gbl_u32*)g, (lds_u32*)l, 16, 0, 0);
}
__device__ __forceinline__ floatx4 mfma_k32(half8 a, half8 b, floatx4 c) {
    return __builtin_amdgcn_mfma_f32_16x16x32_f16(a, b, c, 0, 0, 0);
}
__device__ __forceinline__ floatx4 mfma_k16(half4 a, half4 b, floatx4 c) {
    return __builtin_amdgcn_mfma_f32_16x16x16f16(a, b, c, 0, 0, 0);
}

// ---------- fused prepass (unchanged from R8) ----------
// blocks [0,4096): Qhat = (q*wq+bq)*(wk*scale*log2e)  [wk folded into Q],
//                  Khat = (half)k  [bk dropped: cancels in softmax]
// blocks [4096,5120): Vthat transpose [B*NH][64][HW], Vthat = v*wv [bv dropped]
__global__ __launch_bounds__(256) void prepass_all(
    const float* __restrict__ q_in, const float* __restrict__ k_in,
    const float* __restrict__ v_in,
    const float* __restrict__ wq, const float* __restrict__ bq,
    const float* __restrict__ wk, const float* __restrict__ wv,
    _Float16* __restrict__ Qhat, _Float16* __restrict__ Khat,
    _Float16* __restrict__ Vthat)
{
    if (blockIdx.x < 4096) {
        int idx = (blockIdx.x * 256 + threadIdx.x) * 4;
        int b = idx >> 20;
        int rem = idx & ((1 << 20) - 1);
        int row = rem >> 8;
        int c = rem & 255;
        int h = c >> 6;
        int ch = c & 63;
        floatx4 q4 = *(const floatx4*)(q_in + idx);
        floatx4 k4 = *(const floatx4*)(k_in + idx);
        floatx4 wq4 = *(const floatx4*)(wq + c);
        floatx4 bq4 = *(const floatx4*)(bq + c);
        floatx4 wk4 = *(const floatx4*)(wk + c);
        const float qsc = 0.125f * LOG2E;
        half4 qh, kh;
        qh[0] = (_Float16)((q4.x * wq4.x + bq4.x) * (wk4.x * qsc));
        qh[1] = (_Float16)((q4.y * wq4.y + bq4.y) * (wk4.y * qsc));
        qh[2] = (_Float16)((q4.z * wq4.z + bq4.z) * (wk4.z * qsc));
        qh[3] = (_Float16)((q4.w * wq4.w + bq4.w) * (wk4.w * qsc));
        kh[0] = (_Float16)k4.x;
        kh[1] = (_Float16)k4.y;
        kh[2] = (_Float16)k4.z;
        kh[3] = (_Float16)k4.w;
        size_t o = ((size_t)(b * NH + h) * HW + row) * DH + ch;
        *(half4*)(Qhat + o) = qh;
        *(half4*)(Khat + o) = kh;
    } else {
        __shared__ _Float16 Lt[64 * 68];
        int bx = blockIdx.x - 4096;
        int t = threadIdx.x;
        int key0 = (bx & 63) * 64;
        int bh = bx >> 6;
        int b = bh >> 2, h = bh & 3;
        int c4 = (t & 15) * 4;
        floatx4 wv4 = *(const floatx4*)(wv + h * DH + c4);
        #pragma unroll
        for (int p = 0; p < 4; ++p) {
            int key = p * 16 + (t >> 4);
            const float* vp = v_in + ((size_t)b * HW + key0 + key) * CCH + h * DH + c4;
            floatx4 v4 = *(const floatx4*)vp;
            half4 vh;
            vh[0] = (_Float16)(v4.x * wv4.x);
            vh[1] = (_Float16)(v4.y * wv4.y);
            vh[2] = (_Float16)(v4.z * wv4.z);
            vh[3] = (_Float16)(v4.w * wv4.w);
            *(half4*)(&Lt[key * 68 + c4]) = vh;
        }
        __syncthreads();
        #pragma unroll
        for (int p = 0; p < 2; ++p) {
            int ch = p * 32 + (t >> 3);
            int kg = (t & 7) * 8;
            half8 v8;
            #pragma unroll
            for (int j = 0; j < 8; ++j) v8[j] = Lt[(kg + j) * 68 + ch];
            *(half8*)(Vthat + ((size_t)bh * DH + ch) * HW + key0 + kg) = v8;
        }
    }
}

// ---------- attention (transposed, register-P, QTILE=64) ----------
__launch_bounds__(256, 4)
__global__ void attn_kernel(
    const _Float16* __restrict__ Qhat, const _Float16* __restrict__ Khat,
    const _Float16* __restrict__ Vthat,
    const float* __restrict__ wp, const float* __restrict__ bp,
    const float* __restrict__ bv,
    float* __restrict__ out)
{
    // pool: Ksm0 | Ksm1 | Vsm0 | Vsm1 (8KB each); epilogue reuses as Ot
    __shared__ alignas(16) char pool[32768];
    _Float16* Ksm0 = (_Float16*)(pool);
    _Float16* Ksm1 = (_Float16*)(pool + 8192);
    _Float16* Vsm0 = (_Float16*)(pool + 16384);
    _Float16* Vsm1 = (_Float16*)(pool + 24576);

    const int tid = threadIdx.x;
    const int wave = tid >> 6;
    const int lane = tid & 63;
    const int l15 = lane & 15;
    const int quad = lane >> 4;
    const int ksw = l15 & 7;

    // XCD-locality swizzle: XCD = lin%8 sees only bh in {2c, 2c+1} -> its
    // K/V working set is 2MB (< 4MB L2). Bijective on [0,1024).
    const int lin = blockIdx.x;
    const int bh = (lin & 7) * 2 + ((lin >> 3) & 1);
    const int qtile = lin >> 4;

    // Q B-frags: B[k=ch][n=q], lane holds ch = quad*8+j (+32), q = l15
    const int q0 = qtile * QTILE + wave * 16;
    half8 qfrag[2];
    {
        const _Float16* qp = Qhat + ((size_t)bh * HW + q0 + l15) * DH + quad * 8;
        qfrag[0] = *(const half8*)(qp);
        qfrag[1] = *(const half8*)(qp + 32);
    }

    // staging lane addresses (XOR swizzle of 8-half groups in global addr)
    const int srow0 = lane >> 3;
    const int sw = (lane & 7) ^ srow0;
    const _Float16* kgp0 = Khat + ((size_t)bh * HW + wave * 8 + srow0) * DH + sw * 8;
    const _Float16* kgp1 = kgp0 + (size_t)32 * DH;
    const _Float16* vgp0 = Vthat + ((size_t)bh * DH + wave * 8 + srow0) * HW + sw * 8;
    const _Float16* vgp1 = vgp0 + (size_t)32 * HW;

    floatx4 acc[4];
    float m_i = -1e30f, l_i = 0.0f;
    #pragma unroll
    for (int nt = 0; nt < 4; ++nt) { floatx4 z = {0.f,0.f,0.f,0.f}; acc[nt] = z; }

    #define STAGE(kt, KB, VB) do {                                             \
        gload_lds16(kgp0 + (size_t)(kt) * (KTILE * DH), (KB) + wave * 512);    \
        gload_lds16(kgp1 + (size_t)(kt) * (KTILE * DH), (KB) + 2048 + wave * 512); \
        gload_lds16(vgp0 + (size_t)(kt) * KTILE, (VB) + wave * 512);           \
        gload_lds16(vgp1 + (size_t)(kt) * KTILE, (VB) + 2048 + wave * 512);    \
    } while (0)

    #define COMPUTE(KB, VB) do {                                               \
        floatx4 S[4];                                                          \
        _Pragma("unroll")                                                      \
        for (int kt = 0; kt < 4; ++kt) {                                       \
            const _Float16* kr = (KB) + (l15 + 16 * kt) * 64;                  \
            half8 kf0 = *(const half8*)(kr + ((quad ^ ksw) * 8));              \
            half8 kf1 = *(const half8*)(kr + (((4 + quad) ^ ksw) * 8));        \
            floatx4 s = {0.f, 0.f, 0.f, 0.f};                                  \
            s = mfma_k32(kf0, qfrag[0], s);                                    \
            s = mfma_k32(kf1, qfrag[1], s);                                    \
            S[kt] = s;                                                         \
        }                                                                      \
        half4 pfrag[4];                                                        \
        {                                                                      \
            float mx = fmaxf(fmaxf(fmaxf(S[0][0], S[0][1]),                    \
                                   fmaxf(S[0][2], S[0][3])),                   \
                             fmaxf(fmaxf(S[1][0], S[1][1]),                    \
                                   fmaxf(S[1][2], S[1][3])));                  \
            float mx2 = fmaxf(fmaxf(fmaxf(S[2][0], S[2][1]),                   \
                                    fmaxf(S[2][2], S[2][3])),                  \
                              fmaxf(fmaxf(S[3][0], S[3][1]),                   \
                                    fmaxf(S[3][2], S[3][3])));                 \
            mx = fmaxf(mx, mx2);                                               \
            mx = fmaxf(mx, __shfl_xor(mx, 16));                                \
            mx = fmaxf(mx, __shfl_xor(mx, 32));                                \
            float nm = fmaxf(m_i, mx);                                         \
            float alpha = __builtin_amdgcn_exp2f(m_i - nm);                    \
            float rs = 0.0f;                                                   \
            _Pragma("unroll")                                                  \
            for (int kt = 0; kt < 4; ++kt) {                                   \
                float p0 = __builtin_amdgcn_exp2f(S[kt][0] - nm);              \
                float p1 = __builtin_amdgcn_exp2f(S[kt][1] - nm);              \
                float p2 = __builtin_amdgcn_exp2f(S[kt][2] - nm);              \
                float p3 = __builtin_amdgcn_exp2f(S[kt][3] - nm);              \
                rs += (p0 + p1) + (p2 + p3);                                   \
                pk16x2 lo = __builtin_amdgcn_cvt_pkrtz(p0, p1);                \
                pk16x2 hi = __builtin_amdgcn_cvt_pkrtz(p2, p3);                \
                half4 pk;                                                      \
                pk[0] = (_Float16)lo[0]; pk[1] = (_Float16)lo[1];              \
                pk[2] = (_Float16)hi[0]; pk[3] = (_Float16)hi[1];              \
                pfrag[kt] = pk;                                                \
            }                                                                  \
            rs += __shfl_xor(rs, 16);                                          \
            rs += __shfl_xor(rs, 32);                                          \
            l_i = l_i * alpha + rs;                                            \
            m_i = nm;                                                          \
            _Pragma("unroll")                                                  \
            for (int nt = 0; nt < 4; ++nt) acc[nt] *= alpha;                   \
        }                                                                      \
        _Pragma("unroll")                                                      \
        for (int kt = 0; kt < 4; ++kt) {                                       \
            _Pragma("unroll")                                                  \
            for (int nt = 0; nt < 4; ++nt) {                                   \
                const _Float16* vr = (VB) + (l15 + 16 * nt) * 64               \
                    + (((2 * kt + (quad >> 1)) ^ ksw) * 8) + (quad & 1) * 4;   \
                half4 vf = *(const half4*)vr;                                  \
                acc[nt] = mfma_k16(vf, pfrag[kt], acc[nt]);                    \
            }                                                                  \
        }                                                                      \
    } while (0)

    STAGE(0, Ksm0, Vsm0);
    for (int kt = 0; kt < NKT; kt += 2) {
        __syncthreads();
        if (kt + 1 < NKT) STAGE(kt + 1, Ksm1, Vsm1);
        COMPUTE(Ksm0, Vsm0);
        __syncthreads();
        if (kt + 2 < NKT) STAGE(kt + 2, Ksm0, Vsm0);
        COMPUTE(Ksm1, Vsm1);
    }

    // ---- epilogue: transpose O^T through LDS, coalesced stores ----
    const int b = bh >> 2, h = bh & 3, ch0 = h * DH;
    floatx4 wp4 = *(const floatx4*)(wp + ch0 + l15 * 4);
    floatx4 bp4 = *(const floatx4*)(bp + ch0 + l15 * 4);
    floatx4 bv4 = *(const floatx4*)(bv + ch0 + l15 * 4);
    floatx4 bpe;   // bv enters exactly once: out = (PV/l)*wp + (bv*wp + bp)
    bpe.x = bv4.x * wp4.x + bp4.x;
    bpe.y = bv4.y * wp4.y + bp4.y;
    bpe.z = bv4.z * wp4.z + bp4.z;
    bpe.w = bv4.w * wp4.w + bp4.w;
    const float inv_l = 1.0f / l_i;

    __syncthreads();
    float* Ot = (float*)(pool) + wave * 1152;   // [16 q][72] floats, 4608B/wave
    #pragma unroll
    for (int nt = 0; nt < 4; ++nt) {
        floatx4 o;
        #pragma unroll
        for (int r = 0; r < 4; ++r) o[r] = acc[nt][r] * inv_l;
        *(floatx4*)&Ot[l15 * 72 + nt * 16 + quad * 4] = o;
    }
    #pragma unroll
    for (int i = 0; i < 4; ++i) {
        int q = i * 4 + quad;
        floatx4 v = *(const floatx4*)&Ot[q * 72 + l15 * 4];
        floatx4 o;
        o.x = v.x * wp4.x + bpe.x;
        o.y = v.y * wp4.y + bpe.y;
        o.z = v.z * wp4.z + bpe.z;
        o.w = v.w * wp4.w + bpe.w;
        *(floatx4*)(out + ((size_t)b * HW + q0 + q) * CCH + ch0 + l15 * 4) = o;
    }
    #undef STAGE
    #undef COMPUTE
}

extern "C" void kernel_launch(void* const* d_in, const int* in_sizes, int n_in,
                              void* d_out, int out_size, void* d_ws, size_t ws_size,
                              hipStream_t stream) {
    const float* q_in = (const float*)d_in[0];
    const float* k_in = (const float*)d_in[1];
    const float* v_in = (const float*)d_in[2];
    const float* wq = (const float*)d_in[3];
    const float* bq = (const float*)d_in[4];
    const float* wk = (const float*)d_in[5];
    const float* wv = (const float*)d_in[7];
    const float* bv = (const float*)d_in[8];
    const float* wp = (const float*)d_in[9];
    const float* bp = (const float*)d_in[10];
    float* out = (float*)d_out;

    const size_t tensor_halves = (size_t)4 * NH * HW * DH;
    _Float16* Qhat = (_Float16*)d_ws;
    _Float16* Khat = Qhat + tensor_halves;
    _Float16* Vthat = Khat + tensor_halves;

    prepass_all<<<dim3(4096 + 1024), 256, 0, stream>>>(
        q_in, k_in, v_in, wq, bq, wk, wv, Qhat, Khat, Vthat);
    attn_kernel<<<dim3((HW / QTILE) * 4 * NH), 256, 0, stream>>>(
        Qhat, Khat, Vthat, wp, bp, bv, out);
}

// Round 6
// 222.025 us; speedup vs baseline: 1.0107x; 1.0107x over previous
//
#include <hip/hip_runtime.h>

// SpatialAttention B=4 HW=4096 C=256 NH=4 d=64 — f16 MFMA flash attention.
// R11 = R5 champion attn structure (256 thr, 4 waves, QTILE=128, g=2,
//       __shfl_xor reduces — R10's permlane asm REVERTED, it broke correctness)
//  + XCD-locality swizzle (R9's counters proved FETCH 70->12MB; now applied
//    WITHOUT R9's confounding g=1 change): each XCD sees 2 bh values ->
//    K/V working set 2MB < 4MB L2, staging loads at L2 latency.
//  + fused Q-prep in attn prologue (q_in f32 read once per block; Qhat gone)
//  + prepass identities: bk/bv dropped exactly, wk folded into Q scale
//  + pfrag built via union bit-cast of cvt_pkrtz pairs

#define HW 4096
#define CCH 256
#define DH 64
#define NH 4
#define QTILE 128
#define KTILE 64
#define NKT (HW / KTILE)
#define LOG2E 1.44269504088896340736f

typedef __attribute__((ext_vector_type(8))) _Float16 half8;
typedef __attribute__((ext_vector_type(4))) _Float16 half4;
typedef __attribute__((ext_vector_type(2))) __fp16 pk16x2;   // cvt_pkrtz native type
typedef __attribute__((ext_vector_type(4))) float floatx4;

typedef __attribute__((address_space(1))) const unsigned int gbl_u32;
typedef __attribute__((address_space(3))) unsigned int lds_u32;

__device__ __forceinline__ void gload_lds16(const void* g, void* l) {
    __builtin_amdgcn_global_load_lds((gbl_u32*)g, (lds_u32*)l, 16, 0, 0);
}
__device__ __forceinline__ floatx4 mfma_k32(half8 a, half8 b, floatx4 c) {
    return __builtin_amdgcn_mfma_f32_16x16x32_f16(a, b, c, 0, 0, 0);
}
__device__ __forceinline__ floatx4 mfma_k16(half4 a, half4 b, floatx4 c) {
    return __builtin_amdgcn_mfma_f32_16x16x16f16(a, b, c, 0, 0, 0);
}

// ---------- fused prepass ----------
// blocks [0,4096): Khat = (half)k  [bk dropped: cancels in softmax; wk folded
//                  into the Q scale applied in attn]
// blocks [4096,5120): Vthat transpose [B*NH][64][HW], Vthat = v*wv [bv dropped]
__global__ __launch_bounds__(256) void prepass_all(
    const float* __restrict__ k_in, const float* __restrict__ v_in,
    const float* __restrict__ wv,
    _Float16* __restrict__ Khat, _Float16* __restrict__ Vthat)
{
    if (blockIdx.x < 4096) {
        int idx = (blockIdx.x * 256 + threadIdx.x) * 4;
        int b = idx >> 20;
        int rem = idx & ((1 << 20) - 1);
        int row = rem >> 8;
        int c = rem & 255;
        int h = c >> 6;
        int ch = c & 63;
        floatx4 k4 = *(const floatx4*)(k_in + idx);
        half4 kh;
        kh[0] = (_Float16)k4.x;
        kh[1] = (_Float16)k4.y;
        kh[2] = (_Float16)k4.z;
        kh[3] = (_Float16)k4.w;
        size_t o = ((size_t)(b * NH + h) * HW + row) * DH + ch;
        *(half4*)(Khat + o) = kh;
    } else {
        __shared__ _Float16 Lt[64 * 68];
        int bx = blockIdx.x - 4096;
        int t = threadIdx.x;
        int key0 = (bx & 63) * 64;
        int bh = bx >> 6;
        int b = bh >> 2, h = bh & 3;
        int c4 = (t & 15) * 4;
        floatx4 wv4 = *(const floatx4*)(wv + h * DH + c4);
        #pragma unroll
        for (int p = 0; p < 4; ++p) {
            int key = p * 16 + (t >> 4);
            const float* vp = v_in + ((size_t)b * HW + key0 + key) * CCH + h * DH + c4;
            floatx4 v4 = *(const floatx4*)vp;
            half4 vh;
            vh[0] = (_Float16)(v4.x * wv4.x);
            vh[1] = (_Float16)(v4.y * wv4.y);
            vh[2] = (_Float16)(v4.z * wv4.z);
            vh[3] = (_Float16)(v4.w * wv4.w);
            *(half4*)(&Lt[key * 68 + c4]) = vh;
        }
        __syncthreads();
        #pragma unroll
        for (int p = 0; p < 2; ++p) {
            int ch = p * 32 + (t >> 3);
            int kg = (t & 7) * 8;
            half8 v8;
            #pragma unroll
            for (int j = 0; j < 8; ++j) v8[j] = Lt[(kg + j) * 68 + ch];
            *(half8*)(Vthat + ((size_t)bh * DH + ch) * HW + key0 + kg) = v8;
        }
    }
}

// ---------- attention (transposed, register-P, fused Q-prep, XCD swizzle) ----
__launch_bounds__(256, 3)
__global__ void attn_kernel(
    const float* __restrict__ q_in,
    const _Float16* __restrict__ Khat, const _Float16* __restrict__ Vthat,
    const float* __restrict__ wq, const float* __restrict__ bq,
    const float* __restrict__ wk,
    const float* __restrict__ wp, const float* __restrict__ bp,
    const float* __restrict__ bv,
    float* __restrict__ out)
{
    // pool: Ksm0 | Ksm1 | Vsm0 | Vsm1 (8KB each); epilogue reuses as Ot
    __shared__ alignas(16) char pool[36864];
    _Float16* Ksm0 = (_Float16*)(pool);
    _Float16* Ksm1 = (_Float16*)(pool + 8192);
    _Float16* Vsm0 = (_Float16*)(pool + 16384);
    _Float16* Vsm1 = (_Float16*)(pool + 24576);

    const int tid = threadIdx.x;
    const int wave = tid >> 6;
    const int lane = tid & 63;
    const int l15 = lane & 15;
    const int quad = lane >> 4;
    const int ksw = l15 & 7;

    // XCD-locality swizzle: XCD = lin%8 sees only bh in {2c, 2c+1} -> its K/V
    // working set is 2MB (< 4MB per-XCD L2). Bijective on [0,512):
    // lin = qtile*16 + ((bh&1)<<3) + (bh>>1).
    const int lin = blockIdx.x;
    const int bh = (lin & 7) * 2 + ((lin >> 3) & 1);
    const int qtile = lin >> 4;
    const int b = bh >> 2, h = bh & 3, ch0 = h * DH;

    // Q B-frags: B[k=ch][n=q], lane holds ch = quad*8+j (+32), q = l15 (+16g).
    // Fused prep: qhat = (q*wq + bq) * (wk * 0.125 * log2e), read from q_in f32.
    const int q0 = qtile * QTILE + wave * 32;
    const float qsc = 0.125f * LOG2E;
    half8 qfrag[2][2];
    #pragma unroll
    for (int g = 0; g < 2; ++g) {
        const float* qp = q_in + ((size_t)b * HW + q0 + g * 16 + l15) * CCH + ch0;
        #pragma unroll
        for (int fr = 0; fr < 2; ++fr) {
            const int c = fr * 32 + quad * 8;
            floatx4 qa = *(const floatx4*)(qp + c);
            floatx4 qb = *(const floatx4*)(qp + c + 4);
            floatx4 wa = *(const floatx4*)(wq + ch0 + c);
            floatx4 wb = *(const floatx4*)(wq + ch0 + c + 4);
            floatx4 ba = *(const floatx4*)(bq + ch0 + c);
            floatx4 bb = *(const floatx4*)(bq + ch0 + c + 4);
            floatx4 ka = *(const floatx4*)(wk + ch0 + c);
            floatx4 kb = *(const floatx4*)(wk + ch0 + c + 4);
            half8 qh;
            #pragma unroll
            for (int j = 0; j < 4; ++j) {
                qh[j]     = (_Float16)((qa[j] * wa[j] + ba[j]) * (ka[j] * qsc));
                qh[j + 4] = (_Float16)((qb[j] * wb[j] + bb[j]) * (kb[j] * qsc));
            }
            qfrag[g][fr] = qh;
        }
    }

    // staging lane addresses (XOR swizzle of 8-half groups in global addr)
    const int srow0 = lane >> 3;
    const int sw = (lane & 7) ^ srow0;
    const _Float16* kgp0 = Khat + ((size_t)bh * HW + wave * 8 + srow0) * DH + sw * 8;
    const _Float16* kgp1 = kgp0 + (size_t)32 * DH;
    const _Float16* vgp0 = Vthat + ((size_t)bh * DH + wave * 8 + srow0) * HW + sw * 8;
    const _Float16* vgp1 = vgp0 + (size_t)32 * HW;

    floatx4 acc[2][4];
    float m_i[2], l_i[2];
    #pragma unroll
    for (int g = 0; g < 2; ++g) {
        m_i[g] = -1e30f; l_i[g] = 0.0f;
        #pragma unroll
        for (int nt = 0; nt < 4; ++nt) { floatx4 z = {0.f,0.f,0.f,0.f}; acc[g][nt] = z; }
    }

    #define STAGE(kt, KB, VB) do {                                             \
        gload_lds16(kgp0 + (size_t)(kt) * (KTILE * DH), (KB) + wave * 512);    \
        gload_lds16(kgp1 + (size_t)(kt) * (KTILE * DH), (KB) + 2048 + wave * 512); \
        gload_lds16(vgp0 + (size_t)(kt) * KTILE, (VB) + wave * 512);           \
        gload_lds16(vgp1 + (size_t)(kt) * KTILE, (VB) + 2048 + wave * 512);    \
    } while (0)

    #define COMPUTE(KB, VB) do {                                               \
        floatx4 S[2][4];                                                       \
        _Pragma("unroll")                                                      \
        for (int kt = 0; kt < 4; ++kt) {                                       \
            const _Float16* kr = (KB) + (l15 + 16 * kt) * 64;                  \
            half8 kf0 = *(const half8*)(kr + ((quad ^ ksw) * 8));              \
            half8 kf1 = *(const half8*)(kr + (((4 + quad) ^ ksw) * 8));        \
            _Pragma("unroll")                                                  \
            for (int g = 0; g < 2; ++g) {                                      \
                floatx4 s = {0.f, 0.f, 0.f, 0.f};                              \
                s = mfma_k32(kf0, qfrag[g][0], s);                             \
                s = mfma_k32(kf1, qfrag[g][1], s);                             \
                S[g][kt] = s;                                                  \
            }                                                                  \
        }                                                                      \
        half4 pfrag[2][4];                                                     \
        _Pragma("unroll")                                                      \
        for (int g = 0; g < 2; ++g) {                                          \
            float mx = fmaxf(fmaxf(fmaxf(S[g][0][0], S[g][0][1]),              \
                                   fmaxf(S[g][0][2], S[g][0][3])),             \
                             fmaxf(fmaxf(S[g][1][0], S[g][1][1]),              \
                                   fmaxf(S[g][1][2], S[g][1][3])));            \
            float mx2 = fmaxf(fmaxf(fmaxf(S[g][2][0], S[g][2][1]),             \
                                    fmaxf(S[g][2][2], S[g][2][3])),            \
                              fmaxf(fmaxf(S[g][3][0], S[g][3][1]),             \
                                    fmaxf(S[g][3][2], S[g][3][3])));           \
            mx = fmaxf(mx, mx2);                                               \
            mx = fmaxf(mx, __shfl_xor(mx, 16));                                \
            mx = fmaxf(mx, __shfl_xor(mx, 32));                                \
            float nm = fmaxf(m_i[g], mx);                                      \
            float alpha = __builtin_amdgcn_exp2f(m_i[g] - nm);                 \
            float rs = 0.0f;                                                   \
            _Pragma("unroll")                                                  \
            for (int kt = 0; kt < 4; ++kt) {                                   \
                float p0 = __builtin_amdgcn_exp2f(S[g][kt][0] - nm);           \
                float p1 = __builtin_amdgcn_exp2f(S[g][kt][1] - nm);           \
                float p2 = __builtin_amdgcn_exp2f(S[g][kt][2] - nm);           \
                float p3 = __builtin_amdgcn_exp2f(S[g][kt][3] - nm);           \
                rs += (p0 + p1) + (p2 + p3);                                   \
                pk16x2 lo = __builtin_amdgcn_cvt_pkrtz(p0, p1);                \
                pk16x2 hi = __builtin_amdgcn_cvt_pkrtz(p2, p3);                \
                union { half4 h; pk16x2 p[2]; } pu;                            \
                pu.p[0] = lo; pu.p[1] = hi;                                    \
                pfrag[g][kt] = pu.h;                                           \
            }                                                                  \
            rs += __shfl_xor(rs, 16);                                          \
            rs += __shfl_xor(rs, 32);                                          \
            l_i[g] = l_i[g] * alpha + rs;                                      \
            m_i[g] = nm;                                                       \
            _Pragma("unroll")                                                  \
            for (int nt = 0; nt < 4; ++nt) acc[g][nt] *= alpha;                \
        }                                                                      \
        _Pragma("unroll")                                                      \
        for (int kt = 0; kt < 4; ++kt) {                                       \
            _Pragma("unroll")                                                  \
            for (int nt = 0; nt < 4; ++nt) {                                   \
                const _Float16* vr = (VB) + (l15 + 16 * nt) * 64               \
                    + (((2 * kt + (quad >> 1)) ^ ksw) * 8) + (quad & 1) * 4;   \
                half4 vf = *(const half4*)vr;                                  \
                acc[0][nt] = mfma_k16(vf, pfrag[0][kt], acc[0][nt]);           \
                acc[1][nt] = mfma_k16(vf, pfrag[1][kt], acc[1][nt]);           \
            }                                                                  \
        }                                                                      \
    } while (0)

    STAGE(0, Ksm0, Vsm0);
    for (int kt = 0; kt < NKT; kt += 2) {
        __syncthreads();
        if (kt + 1 < NKT) STAGE(kt + 1, Ksm1, Vsm1);
        COMPUTE(Ksm0, Vsm0);
        __syncthreads();
        if (kt + 2 < NKT) STAGE(kt + 2, Ksm0, Vsm0);
        COMPUTE(Ksm1, Vsm1);
    }

    // ---- epilogue: transpose O^T through LDS, coalesced stores ----
    floatx4 wp4 = *(const floatx4*)(wp + ch0 + l15 * 4);
    floatx4 bp4 = *(const floatx4*)(bp + ch0 + l15 * 4);
    floatx4 bv4 = *(const floatx4*)(bv + ch0 + l15 * 4);
    floatx4 bpe;   // bv enters exactly once: out = (PV/l)*wp + (bv*wp + bp)
    bpe.x = bv4.x * wp4.x + bp4.x;
    bpe.y = bv4.y * wp4.y + bp4.y;
    bpe.z = bv4.z * wp4.z + bp4.z;
    bpe.w = bv4.w * wp4.w + bp4.w;
    float inv_l[2];
    #pragma unroll
    for (int g = 0; g < 2; ++g) inv_l[g] = 1.0f / l_i[g];

    __syncthreads();
    float* Ot = (float*)(pool) + wave * 2304;   // [32 q][72] floats, 9216B/wave
    #pragma unroll
    for (int g = 0; g < 2; ++g) {
        #pragma unroll
        for (int nt = 0; nt < 4; ++nt) {
            floatx4 o;
            #pragma unroll
            for (int r = 0; r < 4; ++r) o[r] = acc[g][nt][r] * inv_l[g];
            *(floatx4*)&Ot[(g * 16 + l15) * 72 + nt * 16 + quad * 4] = o;
        }
    }
    #pragma unroll
    for (int i = 0; i < 8; ++i) {
        int q = i * 4 + quad;
        floatx4 v = *(const floatx4*)&Ot[q * 72 + l15 * 4];
        floatx4 o;
        o.x = v.x * wp4.x + bpe.x;
        o.y = v.y * wp4.y + bpe.y;
        o.z = v.z * wp4.z + bpe.z;
        o.w = v.w * wp4.w + bpe.w;
        *(floatx4*)(out + ((size_t)b * HW + q0 + q) * CCH + ch0 + l15 * 4) = o;
    }
    #undef STAGE
    #undef COMPUTE
}

extern "C" void kernel_launch(void* const* d_in, const int* in_sizes, int n_in,
                              void* d_out, int out_size, void* d_ws, size_t ws_size,
                              hipStream_t stream) {
    const float* q_in = (const float*)d_in[0];
    const float* k_in = (const float*)d_in[1];
    const float* v_in = (const float*)d_in[2];
    const float* wq = (const float*)d_in[3];
    const float* bq = (const float*)d_in[4];
    const float* wk = (const float*)d_in[5];
    const float* wv = (const float*)d_in[7];
    const float* bv = (const float*)d_in[8];
    const float* wp = (const float*)d_in[9];
    const float* bp = (const float*)d_in[10];
    float* out = (float*)d_out;

    const size_t tensor_halves = (size_t)4 * NH * HW * DH;
    _Float16* Khat = (_Float16*)d_ws;
    _Float16* Vthat = Khat + tensor_halves;

    prepass_all<<<dim3(4096 + 1024), 256, 0, stream>>>(
        k_in, v_in, wv, Khat, Vthat);
    attn_kernel<<<dim3((HW / QTILE) * 4 * NH), 256, 0, stream>>>(
        q_in, Khat, Vthat, wq, bq, wk, wp, bp, bv, out);
}

// Round 7
// 220.134 us; speedup vs baseline: 1.0194x; 1.0086x over previous
//
#include <hip/hip_runtime.h>

// SpatialAttention B=4 HW=4096 C=256 NH=4 d=64 — f16 MFMA flash attention.
// R12 = R11 minus the XCD swizzle (one-variable change).
//   Evidence: R9+R11 both carried the swizzle and both regressed ~13% despite
//   FETCH collapsing 70->16MB — L2 same-line contention when 64 blocks/XCD
//   share 2MB beats the L3-spread baseline. Restore R5's 2D grid.
//   Kept from R11 (all low-risk, verified passing):
//   - fused Q-prep in attn prologue (Qhat eliminated; -24MB prepass traffic)
//   - prepass identities: bk/bv dropped exactly, wk folded into Q scale
//   - bpe epilogue (bv enters once via Σatt=1)
//   - pfrag via union bit-cast of cvt_pkrtz pairs
// attn COMPUTE body is byte-identical to the 124.7µs R5 champion.

#define HW 4096
#define CCH 256
#define DH 64
#define NH 4
#define QTILE 128
#define KTILE 64
#define NKT (HW / KTILE)
#define LOG2E 1.44269504088896340736f

typedef __attribute__((ext_vector_type(8))) _Float16 half8;
typedef __attribute__((ext_vector_type(4))) _Float16 half4;
typedef __attribute__((ext_vector_type(2))) __fp16 pk16x2;   // cvt_pkrtz native type
typedef __attribute__((ext_vector_type(4))) float floatx4;

typedef __attribute__((address_space(1))) const unsigned int gbl_u32;
typedef __attribute__((address_space(3))) unsigned int lds_u32;

__device__ __forceinline__ void gload_lds16(const void* g, void* l) {
    __builtin_amdgcn_global_load_lds((gbl_u32*)g, (lds_u32*)l, 16, 0, 0);
}
__device__ __forceinline__ floatx4 mfma_k32(half8 a, half8 b, floatx4 c) {
    return __builtin_amdgcn_mfma_f32_16x16x32_f16(a, b, c, 0, 0, 0);
}
__device__ __forceinline__ floatx4 mfma_k16(half4 a, half4 b, floatx4 c) {
    return __builtin_amdgcn_mfma_f32_16x16x16f16(a, b, c, 0, 0, 0);
}

// ---------- fused prepass ----------
// blocks [0,4096): Khat = (half)k  [bk dropped: cancels in softmax; wk folded
//                  into the Q scale applied in attn]
// blocks [4096,5120): Vthat transpose [B*NH][64][HW], Vthat = v*wv [bv dropped]
__global__ __launch_bounds__(256) void prepass_all(
    const float* __restrict__ k_in, const float* __restrict__ v_in,
    const float* __restrict__ wv,
    _Float16* __restrict__ Khat, _Float16* __restrict__ Vthat)
{
    if (blockIdx.x < 4096) {
        int idx = (blockIdx.x * 256 + threadIdx.x) * 4;
        int b = idx >> 20;
        int rem = idx & ((1 << 20) - 1);
        int row = rem >> 8;
        int c = rem & 255;
        int h = c >> 6;
        int ch = c & 63;
        floatx4 k4 = *(const floatx4*)(k_in + idx);
        half4 kh;
        kh[0] = (_Float16)k4.x;
        kh[1] = (_Float16)k4.y;
        kh[2] = (_Float16)k4.z;
        kh[3] = (_Float16)k4.w;
        size_t o = ((size_t)(b * NH + h) * HW + row) * DH + ch;
        *(half4*)(Khat + o) = kh;
    } else {
        __shared__ _Float16 Lt[64 * 68];
        int bx = blockIdx.x - 4096;
        int t = threadIdx.x;
        int key0 = (bx & 63) * 64;
        int bh = bx >> 6;
        int b = bh >> 2, h = bh & 3;
        int c4 = (t & 15) * 4;
        floatx4 wv4 = *(const floatx4*)(wv + h * DH + c4);
        #pragma unroll
        for (int p = 0; p < 4; ++p) {
            int key = p * 16 + (t >> 4);
            const float* vp = v_in + ((size_t)b * HW + key0 + key) * CCH + h * DH + c4;
            floatx4 v4 = *(const floatx4*)vp;
            half4 vh;
            vh[0] = (_Float16)(v4.x * wv4.x);
            vh[1] = (_Float16)(v4.y * wv4.y);
            vh[2] = (_Float16)(v4.z * wv4.z);
            vh[3] = (_Float16)(v4.w * wv4.w);
            *(half4*)(&Lt[key * 68 + c4]) = vh;
        }
        __syncthreads();
        #pragma unroll
        for (int p = 0; p < 2; ++p) {
            int ch = p * 32 + (t >> 3);
            int kg = (t & 7) * 8;
            half8 v8;
            #pragma unroll
            for (int j = 0; j < 8; ++j) v8[j] = Lt[(kg + j) * 68 + ch];
            *(half8*)(Vthat + ((size_t)bh * DH + ch) * HW + key0 + kg) = v8;
        }
    }
}

// ---------- attention (transposed, register-P, fused Q-prep) ----------
__launch_bounds__(256, 3)
__global__ void attn_kernel(
    const float* __restrict__ q_in,
    const _Float16* __restrict__ Khat, const _Float16* __restrict__ Vthat,
    const float* __restrict__ wq, const float* __restrict__ bq,
    const float* __restrict__ wk,
    const float* __restrict__ wp, const float* __restrict__ bp,
    const float* __restrict__ bv,
    float* __restrict__ out)
{
    // pool: Ksm0 | Ksm1 | Vsm0 | Vsm1 (8KB each); epilogue reuses as Ot
    __shared__ alignas(16) char pool[36864];
    _Float16* Ksm0 = (_Float16*)(pool);
    _Float16* Ksm1 = (_Float16*)(pool + 8192);
    _Float16* Vsm0 = (_Float16*)(pool + 16384);
    _Float16* Vsm1 = (_Float16*)(pool + 24576);

    const int tid = threadIdx.x;
    const int wave = tid >> 6;
    const int lane = tid & 63;
    const int l15 = lane & 15;
    const int quad = lane >> 4;
    const int ksw = l15 & 7;

    const int qtile = blockIdx.x;
    const int bh = blockIdx.y;
    const int b = bh >> 2, h = bh & 3, ch0 = h * DH;

    // Q B-frags: B[k=ch][n=q], lane holds ch = quad*8+j (+32), q = l15 (+16g).
    // Fused prep: qhat = (q*wq + bq) * (wk * 0.125 * log2e), read from q_in f32.
    const int q0 = qtile * QTILE + wave * 32;
    const float qsc = 0.125f * LOG2E;
    half8 qfrag[2][2];
    #pragma unroll
    for (int g = 0; g < 2; ++g) {
        const float* qp = q_in + ((size_t)b * HW + q0 + g * 16 + l15) * CCH + ch0;
        #pragma unroll
        for (int fr = 0; fr < 2; ++fr) {
            const int c = fr * 32 + quad * 8;
            floatx4 qa = *(const floatx4*)(qp + c);
            floatx4 qb = *(const floatx4*)(qp + c + 4);
            floatx4 wa = *(const floatx4*)(wq + ch0 + c);
            floatx4 wb = *(const floatx4*)(wq + ch0 + c + 4);
            floatx4 ba = *(const floatx4*)(bq + ch0 + c);
            floatx4 bb = *(const floatx4*)(bq + ch0 + c + 4);
            floatx4 ka = *(const floatx4*)(wk + ch0 + c);
            floatx4 kb = *(const floatx4*)(wk + ch0 + c + 4);
            half8 qh;
            #pragma unroll
            for (int j = 0; j < 4; ++j) {
                qh[j]     = (_Float16)((qa[j] * wa[j] + ba[j]) * (ka[j] * qsc));
                qh[j + 4] = (_Float16)((qb[j] * wb[j] + bb[j]) * (kb[j] * qsc));
            }
            qfrag[g][fr] = qh;
        }
    }

    // staging lane addresses (XOR swizzle of 8-half groups in global addr)
    const int srow0 = lane >> 3;
    const int sw = (lane & 7) ^ srow0;
    const _Float16* kgp0 = Khat + ((size_t)bh * HW + wave * 8 + srow0) * DH + sw * 8;
    const _Float16* kgp1 = kgp0 + (size_t)32 * DH;
    const _Float16* vgp0 = Vthat + ((size_t)bh * DH + wave * 8 + srow0) * HW + sw * 8;
    const _Float16* vgp1 = vgp0 + (size_t)32 * HW;

    floatx4 acc[2][4];
    float m_i[2], l_i[2];
    #pragma unroll
    for (int g = 0; g < 2; ++g) {
        m_i[g] = -1e30f; l_i[g] = 0.0f;
        #pragma unroll
        for (int nt = 0; nt < 4; ++nt) { floatx4 z = {0.f,0.f,0.f,0.f}; acc[g][nt] = z; }
    }

    #define STAGE(kt, KB, VB) do {                                             \
        gload_lds16(kgp0 + (size_t)(kt) * (KTILE * DH), (KB) + wave * 512);    \
        gload_lds16(kgp1 + (size_t)(kt) * (KTILE * DH), (KB) + 2048 + wave * 512); \
        gload_lds16(vgp0 + (size_t)(kt) * KTILE, (VB) + wave * 512);           \
        gload_lds16(vgp1 + (size_t)(kt) * KTILE, (VB) + 2048 + wave * 512);    \
    } while (0)

    #define COMPUTE(KB, VB) do {                                               \
        floatx4 S[2][4];                                                       \
        _Pragma("unroll")                                                      \
        for (int kt = 0; kt < 4; ++kt) {                                       \
            const _Float16* kr = (KB) + (l15 + 16 * kt) * 64;                  \
            half8 kf0 = *(const half8*)(kr + ((quad ^ ksw) * 8));              \
            half8 kf1 = *(const half8*)(kr + (((4 + quad) ^ ksw) * 8));        \
            _Pragma("unroll")                                                  \
            for (int g = 0; g < 2; ++g) {                                      \
                floatx4 s = {0.f, 0.f, 0.f, 0.f};                              \
                s = mfma_k32(kf0, qfrag[g][0], s);                             \
                s = mfma_k32(kf1, qfrag[g][1], s);                             \
                S[g][kt] = s;                                                  \
            }                                                                  \
        }                                                                      \
        half4 pfrag[2][4];                                                     \
        _Pragma("unroll")                                                      \
        for (int g = 0; g < 2; ++g) {                                          \
            float mx = fmaxf(fmaxf(fmaxf(S[g][0][0], S[g][0][1]),              \
                                   fmaxf(S[g][0][2], S[g][0][3])),             \
                             fmaxf(fmaxf(S[g][1][0], S[g][1][1]),              \
                                   fmaxf(S[g][1][2], S[g][1][3])));            \
            float mx2 = fmaxf(fmaxf(fmaxf(S[g][2][0], S[g][2][1]),             \
                                    fmaxf(S[g][2][2], S[g][2][3])),            \
                              fmaxf(fmaxf(S[g][3][0], S[g][3][1]),             \
                                    fmaxf(S[g][3][2], S[g][3][3])));           \
            mx = fmaxf(mx, mx2);                                               \
            mx = fmaxf(mx, __shfl_xor(mx, 16));                                \
            mx = fmaxf(mx, __shfl_xor(mx, 32));                                \
            float nm = fmaxf(m_i[g], mx);                                      \
            float alpha = __builtin_amdgcn_exp2f(m_i[g] - nm);                 \
            float rs = 0.0f;                                                   \
            _Pragma("unroll")                                                  \
            for (int kt = 0; kt < 4; ++kt) {                                   \
                float p0 = __builtin_amdgcn_exp2f(S[g][kt][0] - nm);           \
                float p1 = __builtin_amdgcn_exp2f(S[g][kt][1] - nm);           \
                float p2 = __builtin_amdgcn_exp2f(S[g][kt][2] - nm);           \
                float p3 = __builtin_amdgcn_exp2f(S[g][kt][3] - nm);           \
                rs += (p0 + p1) + (p2 + p3);                                   \
                pk16x2 lo = __builtin_amdgcn_cvt_pkrtz(p0, p1);                \
                pk16x2 hi = __builtin_amdgcn_cvt_pkrtz(p2, p3);                \
                union { half4 h; pk16x2 p[2]; } pu;                            \
                pu.p[0] = lo; pu.p[1] = hi;                                    \
                pfrag[g][kt] = pu.h;                                           \
            }                                                                  \
            rs += __shfl_xor(rs, 16);                                          \
            rs += __shfl_xor(rs, 32);                                          \
            l_i[g] = l_i[g] * alpha + rs;                                      \
            m_i[g] = nm;                                                       \
            _Pragma("unroll")                                                  \
            for (int nt = 0; nt < 4; ++nt) acc[g][nt] *= alpha;                \
        }                                                                      \
        _Pragma("unroll")                                                      \
        for (int kt = 0; kt < 4; ++kt) {                                       \
            _Pragma("unroll")                                                  \
            for (int nt = 0; nt < 4; ++nt) {                                   \
                const _Float16* vr = (VB) + (l15 + 16 * nt) * 64               \
                    + (((2 * kt + (quad >> 1)) ^ ksw) * 8) + (quad & 1) * 4;   \
                half4 vf = *(const half4*)vr;                                  \
                acc[0][nt] = mfma_k16(vf, pfrag[0][kt], acc[0][nt]);           \
                acc[1][nt] = mfma_k16(vf, pfrag[1][kt], acc[1][nt]);           \
            }                                                                  \
        }                                                                      \
    } while (0)

    STAGE(0, Ksm0, Vsm0);
    for (int kt = 0; kt < NKT; kt += 2) {
        __syncthreads();
        if (kt + 1 < NKT) STAGE(kt + 1, Ksm1, Vsm1);
        COMPUTE(Ksm0, Vsm0);
        __syncthreads();
        if (kt + 2 < NKT) STAGE(kt + 2, Ksm0, Vsm0);
        COMPUTE(Ksm1, Vsm1);
    }

    // ---- epilogue: transpose O^T through LDS, coalesced stores ----
    floatx4 wp4 = *(const floatx4*)(wp + ch0 + l15 * 4);
    floatx4 bp4 = *(const floatx4*)(bp + ch0 + l15 * 4);
    floatx4 bv4 = *(const floatx4*)(bv + ch0 + l15 * 4);
    floatx4 bpe;   // bv enters exactly once: out = (PV/l)*wp + (bv*wp + bp)
    bpe.x = bv4.x * wp4.x + bp4.x;
    bpe.y = bv4.y * wp4.y + bp4.y;
    bpe.z = bv4.z * wp4.z + bp4.z;
    bpe.w = bv4.w * wp4.w + bp4.w;
    float inv_l[2];
    #pragma unroll
    for (int g = 0; g < 2; ++g) inv_l[g] = 1.0f / l_i[g];

    __syncthreads();
    float* Ot = (float*)(pool) + wave * 2304;   // [32 q][72] floats, 9216B/wave
    #pragma unroll
    for (int g = 0; g < 2; ++g) {
        #pragma unroll
        for (int nt = 0; nt < 4; ++nt) {
            floatx4 o;
            #pragma unroll
            for (int r = 0; r < 4; ++r) o[r] = acc[g][nt][r] * inv_l[g];
            *(floatx4*)&Ot[(g * 16 + l15) * 72 + nt * 16 + quad * 4] = o;
        }
    }
    #pragma unroll
    for (int i = 0; i < 8; ++i) {
        int q = i * 4 + quad;
        floatx4 v = *(const floatx4*)&Ot[q * 72 + l15 * 4];
        floatx4 o;
        o.x = v.x * wp4.x + bpe.x;
        o.y = v.y * wp4.y + bpe.y;
        o.z = v.z * wp4.z + bpe.z;
        o.w = v.w * wp4.w + bpe.w;
        *(floatx4*)(out + ((size_t)b * HW + q0 + q) * CCH + ch0 + l15 * 4) = o;
    }
    #undef STAGE
    #undef COMPUTE
}

extern "C" void kernel_launch(void* const* d_in, const int* in_sizes, int n_in,
                              void* d_out, int out_size, void* d_ws, size_t ws_size,
                              hipStream_t stream) {
    const float* q_in = (const float*)d_in[0];
    const float* k_in = (const float*)d_in[1];
    const float* v_in = (const float*)d_in[2];
    const float* wq = (const float*)d_in[3];
    const float* bq = (const float*)d_in[4];
    const float* wk = (const float*)d_in[5];
    const float* wv = (const float*)d_in[7];
    const float* bv = (const float*)d_in[8];
    const float* wp = (const float*)d_in[9];
    const float* bp = (const float*)d_in[10];
    float* out = (float*)d_out;

    const size_t tensor_halves = (size_t)4 * NH * HW * DH;
    _Float16* Khat = (_Float16*)d_ws;
    _Float16* Vthat = Khat + tensor_halves;

    prepass_all<<<dim3(4096 + 1024), 256, 0, stream>>>(
        k_in, v_in, wv, Khat, Vthat);
    attn_kernel<<<dim3(HW / QTILE, 4 * NH), 256, 0, stream>>>(
        q_in, Khat, Vthat, wq, bq, wk, wp, bp, bv, out);
}

// Round 8
// 215.142 us; speedup vs baseline: 1.0430x; 1.0232x over previous
//
#include <hip/hip_runtime.h>

// SpatialAttention B=4 HW=4096 C=256 NH=4 d=64 — f16 MFMA flash attention.
// R13 = attn kernel BYTE-IDENTICAL to the 124.7µs R5 champion (round-0 input).
//   Single variable vs champion: lightened prepass —
//     Qhat = (q*wq+bq)*(wk*qsc)   [wk folded in; bk dropped exactly — the
//                                  q̂·bk term is constant per q-row and
//                                  cancels in softmax]
//     Khat = (half)k              [no scale/bias needed]
//     Vthat = v*wv + bv           [kept — epilogue stays wp/bp-only]
//   R11/R12's fused Q-prep + union pfrag are OUT (their shared ~14µs attn
//   regression); swizzle OUT (proven perf-neutral, R12); bpe epilogue OUT.

#define HW 4096
#define CCH 256
#define DH 64
#define NH 4
#define QTILE 128
#define KTILE 64
#define NKT (HW / KTILE)
#define LOG2E 1.44269504088896340736f

typedef __attribute__((ext_vector_type(8))) _Float16 half8;
typedef __attribute__((ext_vector_type(4))) _Float16 half4;
typedef __attribute__((ext_vector_type(2))) __fp16 pk16x2;   // cvt_pkrtz native type
typedef __attribute__((ext_vector_type(4))) float floatx4;

typedef __attribute__((address_space(1))) const unsigned int gbl_u32;
typedef __attribute__((address_space(3))) unsigned int lds_u32;

__device__ __forceinline__ void gload_lds16(const void* g, void* l) {
    __builtin_amdgcn_global_load_lds((gbl_u32*)g, (lds_u32*)l, 16, 0, 0);
}
__device__ __forceinline__ floatx4 mfma_k32(half8 a, half8 b, floatx4 c) {
    return __builtin_amdgcn_mfma_f32_16x16x32_f16(a, b, c, 0, 0, 0);
}
__device__ __forceinline__ floatx4 mfma_k16(half4 a, half4 b, floatx4 c) {
    return __builtin_amdgcn_mfma_f32_16x16x16f16(a, b, c, 0, 0, 0);
}

// ---------- fused prepass ----------
// blocks [0,4096): Qhat = (q*wq+bq)*(wk*scale*log2e), Khat = (half)k
// blocks [4096,5120): Vthat transpose [B*NH][64][HW], Vthat = v*wv + bv
__global__ __launch_bounds__(256) void prepass_all(
    const float* __restrict__ q_in, const float* __restrict__ k_in,
    const float* __restrict__ v_in,
    const float* __restrict__ wq, const float* __restrict__ bq,
    const float* __restrict__ wk,
    const float* __restrict__ wv, const float* __restrict__ bv,
    _Float16* __restrict__ Qhat, _Float16* __restrict__ Khat,
    _Float16* __restrict__ Vthat)
{
    if (blockIdx.x < 4096) {
        int idx = (blockIdx.x * 256 + threadIdx.x) * 4;
        int b = idx >> 20;
        int rem = idx & ((1 << 20) - 1);
        int row = rem >> 8;
        int c = rem & 255;
        int h = c >> 6;
        int ch = c & 63;
        floatx4 q4 = *(const floatx4*)(q_in + idx);
        floatx4 k4 = *(const floatx4*)(k_in + idx);
        floatx4 wq4 = *(const floatx4*)(wq + c);
        floatx4 bq4 = *(const floatx4*)(bq + c);
        floatx4 wk4 = *(const floatx4*)(wk + c);
        const float qsc = 0.125f * LOG2E;
        half4 qh, kh;
        qh[0] = (_Float16)((q4.x * wq4.x + bq4.x) * (wk4.x * qsc));
        qh[1] = (_Float16)((q4.y * wq4.y + bq4.y) * (wk4.y * qsc));
        qh[2] = (_Float16)((q4.z * wq4.z + bq4.z) * (wk4.z * qsc));
        qh[3] = (_Float16)((q4.w * wq4.w + bq4.w) * (wk4.w * qsc));
        kh[0] = (_Float16)k4.x;
        kh[1] = (_Float16)k4.y;
        kh[2] = (_Float16)k4.z;
        kh[3] = (_Float16)k4.w;
        size_t o = ((size_t)(b * NH + h) * HW + row) * DH + ch;
        *(half4*)(Qhat + o) = qh;
        *(half4*)(Khat + o) = kh;
    } else {
        __shared__ _Float16 Lt[64 * 68];
        int bx = blockIdx.x - 4096;
        int t = threadIdx.x;
        int key0 = (bx & 63) * 64;
        int bh = bx >> 6;
        int b = bh >> 2, h = bh & 3;
        int c4 = (t & 15) * 4;
        floatx4 wv4 = *(const floatx4*)(wv + h * DH + c4);
        floatx4 bv4 = *(const floatx4*)(bv + h * DH + c4);
        #pragma unroll
        for (int p = 0; p < 4; ++p) {
            int key = p * 16 + (t >> 4);
            const float* vp = v_in + ((size_t)b * HW + key0 + key) * CCH + h * DH + c4;
            floatx4 v4 = *(const floatx4*)vp;
            half4 vh;
            vh[0] = (_Float16)(v4.x * wv4.x + bv4.x);
            vh[1] = (_Float16)(v4.y * wv4.y + bv4.y);
            vh[2] = (_Float16)(v4.z * wv4.z + bv4.z);
            vh[3] = (_Float16)(v4.w * wv4.w + bv4.w);
            *(half4*)(&Lt[key * 68 + c4]) = vh;
        }
        __syncthreads();
        #pragma unroll
        for (int p = 0; p < 2; ++p) {
            int ch = p * 32 + (t >> 3);
            int kg = (t & 7) * 8;
            half8 v8;
            #pragma unroll
            for (int j = 0; j < 8; ++j) v8[j] = Lt[(kg + j) * 68 + ch];
            *(half8*)(Vthat + ((size_t)bh * DH + ch) * HW + key0 + kg) = v8;
        }
    }
}

// ---------- attention (transposed, register-P) — byte-identical to R5 ----------
__launch_bounds__(256, 3)
__global__ void attn_kernel(
    const _Float16* __restrict__ Qhat, const _Float16* __restrict__ Khat,
    const _Float16* __restrict__ Vthat,
    const float* __restrict__ wp, const float* __restrict__ bp,
    float* __restrict__ out)
{
    // pool: Ksm0 | Ksm1 | Vsm0 | Vsm1 (8KB each); epilogue reuses as Ot
    __shared__ alignas(16) char pool[36864];
    _Float16* Ksm0 = (_Float16*)(pool);
    _Float16* Ksm1 = (_Float16*)(pool + 8192);
    _Float16* Vsm0 = (_Float16*)(pool + 16384);
    _Float16* Vsm1 = (_Float16*)(pool + 24576);

    const int tid = threadIdx.x;
    const int wave = tid >> 6;
    const int lane = tid & 63;
    const int l15 = lane & 15;
    const int quad = lane >> 4;
    const int ksw = l15 & 7;

    const int qtile = blockIdx.x;
    const int bh = blockIdx.y;

    // Q B-frags: B[k=ch][n=q], lane holds ch = quad*8+j (+32), q = l15 (+16g)
    const int q0 = qtile * QTILE + wave * 32;
    half8 qfrag[2][2];
    #pragma unroll
    for (int g = 0; g < 2; ++g) {
        const _Float16* qp = Qhat + ((size_t)bh * HW + q0 + g * 16 + l15) * DH + quad * 8;
        qfrag[g][0] = *(const half8*)(qp);
        qfrag[g][1] = *(const half8*)(qp + 32);
    }

    // staging lane addresses (XOR swizzle of 8-half groups in global addr)
    const int srow0 = lane >> 3;
    const int sw = (lane & 7) ^ srow0;
    const _Float16* kgp0 = Khat + ((size_t)bh * HW + wave * 8 + srow0) * DH + sw * 8;
    const _Float16* kgp1 = kgp0 + (size_t)32 * DH;
    const _Float16* vgp0 = Vthat + ((size_t)bh * DH + wave * 8 + srow0) * HW + sw * 8;
    const _Float16* vgp1 = vgp0 + (size_t)32 * HW;

    floatx4 acc[2][4];
    float m_i[2], l_i[2];
    #pragma unroll
    for (int g = 0; g < 2; ++g) {
        m_i[g] = -1e30f; l_i[g] = 0.0f;
        #pragma unroll
        for (int nt = 0; nt < 4; ++nt) { floatx4 z = {0.f,0.f,0.f,0.f}; acc[g][nt] = z; }
    }

    #define STAGE(kt, KB, VB) do {                                             \
        gload_lds16(kgp0 + (size_t)(kt) * (KTILE * DH), (KB) + wave * 512);    \
        gload_lds16(kgp1 + (size_t)(kt) * (KTILE * DH), (KB) + 2048 + wave * 512); \
        gload_lds16(vgp0 + (size_t)(kt) * KTILE, (VB) + wave * 512);           \
        gload_lds16(vgp1 + (size_t)(kt) * KTILE, (VB) + 2048 + wave * 512);    \
    } while (0)

    #define COMPUTE(KB, VB) do {                                               \
        floatx4 S[2][4];                                                       \
        _Pragma("unroll")                                                      \
        for (int kt = 0; kt < 4; ++kt) {                                       \
            const _Float16* kr = (KB) + (l15 + 16 * kt) * 64;                  \
            half8 kf0 = *(const half8*)(kr + ((quad ^ ksw) * 8));              \
            half8 kf1 = *(const half8*)(kr + (((4 + quad) ^ ksw) * 8));        \
            _Pragma("unroll")                                                  \
            for (int g = 0; g < 2; ++g) {                                      \
                floatx4 s = {0.f, 0.f, 0.f, 0.f};                              \
                s = mfma_k32(kf0, qfrag[g][0], s);                             \
                s = mfma_k32(kf1, qfrag[g][1], s);                             \
                S[g][kt] = s;                                                  \
            }                                                                  \
        }                                                                      \
        half4 pfrag[2][4];                                                     \
        _Pragma("unroll")                                                      \
        for (int g = 0; g < 2; ++g) {                                          \
            float mx = fmaxf(fmaxf(fmaxf(S[g][0][0], S[g][0][1]),              \
                                   fmaxf(S[g][0][2], S[g][0][3])),             \
                             fmaxf(fmaxf(S[g][1][0], S[g][1][1]),              \
                                   fmaxf(S[g][1][2], S[g][1][3])));            \
            float mx2 = fmaxf(fmaxf(fmaxf(S[g][2][0], S[g][2][1]),             \
                                    fmaxf(S[g][2][2], S[g][2][3])),            \
                              fmaxf(fmaxf(S[g][3][0], S[g][3][1]),             \
                                    fmaxf(S[g][3][2], S[g][3][3])));           \
            mx = fmaxf(mx, mx2);                                               \
            mx = fmaxf(mx, __shfl_xor(mx, 16));                                \
            mx = fmaxf(mx, __shfl_xor(mx, 32));                                \
            float nm = fmaxf(m_i[g], mx);                                      \
            float alpha = __builtin_amdgcn_exp2f(m_i[g] - nm);                 \
            float rs = 0.0f;                                                   \
            _Pragma("unroll")                                                  \
            for (int kt = 0; kt < 4; ++kt) {                                   \
                float p0 = __builtin_amdgcn_exp2f(S[g][kt][0] - nm);           \
                float p1 = __builtin_amdgcn_exp2f(S[g][kt][1] - nm);           \
                float p2 = __builtin_amdgcn_exp2f(S[g][kt][2] - nm);           \
                float p3 = __builtin_amdgcn_exp2f(S[g][kt][3] - nm);           \
                rs += (p0 + p1) + (p2 + p3);                                   \
                pk16x2 lo = __builtin_amdgcn_cvt_pkrtz(p0, p1);                \
                pk16x2 hi = __builtin_amdgcn_cvt_pkrtz(p2, p3);                \
                half4 pk;                                                      \
                pk[0] = (_Float16)lo[0]; pk[1] = (_Float16)lo[1];              \
                pk[2] = (_Float16)hi[0]; pk[3] = (_Float16)hi[1];              \
                pfrag[g][kt] = pk;                                             \
            }                                                                  \
            rs += __shfl_xor(rs, 16);                                          \
            rs += __shfl_xor(rs, 32);                                          \
            l_i[g] = l_i[g] * alpha + rs;                                      \
            m_i[g] = nm;                                                       \
            _Pragma("unroll")                                                  \
            for (int nt = 0; nt < 4; ++nt) acc[g][nt] *= alpha;                \
        }                                                                      \
        _Pragma("unroll")                                                      \
        for (int kt = 0; kt < 4; ++kt) {                                       \
            _Pragma("unroll")                                                  \
            for (int nt = 0; nt < 4; ++nt) {                                   \
                const _Float16* vr = (VB) + (l15 + 16 * nt) * 64               \
                    + (((2 * kt + (quad >> 1)) ^ ksw) * 8) + (quad & 1) * 4;   \
                half4 vf = *(const half4*)vr;                                  \
                acc[0][nt] = mfma_k16(vf, pfrag[0][kt], acc[0][nt]);           \
                acc[1][nt] = mfma_k16(vf, pfrag[1][kt], acc[1][nt]);           \
            }                                                                  \
        }                                                                      \
    } while (0)

    STAGE(0, Ksm0, Vsm0);
    for (int kt = 0; kt < NKT; kt += 2) {
        __syncthreads();
        if (kt + 1 < NKT) STAGE(kt + 1, Ksm1, Vsm1);
        COMPUTE(Ksm0, Vsm0);
        __syncthreads();
        if (kt + 2 < NKT) STAGE(kt + 2, Ksm0, Vsm0);
        COMPUTE(Ksm1, Vsm1);
    }

    // ---- epilogue: transpose O^T through LDS, coalesced stores ----
    const int b = bh >> 2, h = bh & 3, ch0 = h * DH;
    floatx4 wp4 = *(const floatx4*)(wp + ch0 + l15 * 4);
    floatx4 bp4 = *(const floatx4*)(bp + ch0 + l15 * 4);
    float inv_l[2];
    #pragma unroll
    for (int g = 0; g < 2; ++g) inv_l[g] = 1.0f / l_i[g];

    __syncthreads();
    float* Ot = (float*)(pool) + wave * 2304;   // [32 q][72] floats, 9216B/wave
    #pragma unroll
    for (int g = 0; g < 2; ++g) {
        #pragma unroll
        for (int nt = 0; nt < 4; ++nt) {
            floatx4 o;
            #pragma unroll
            for (int r = 0; r < 4; ++r) o[r] = acc[g][nt][r] * inv_l[g];
            *(floatx4*)&Ot[(g * 16 + l15) * 72 + nt * 16 + quad * 4] = o;
        }
    }
    #pragma unroll
    for (int i = 0; i < 8; ++i) {
        int q = i * 4 + quad;
        floatx4 v = *(const floatx4*)&Ot[q * 72 + l15 * 4];
        floatx4 o;
        o.x = v.x * wp4.x + bp4.x;
        o.y = v.y * wp4.y + bp4.y;
        o.z = v.z * wp4.z + bp4.z;
        o.w = v.w * wp4.w + bp4.w;
        *(floatx4*)(out + ((size_t)b * HW + q0 + q) * CCH + ch0 + l15 * 4) = o;
    }
    #undef STAGE
    #undef COMPUTE
}

extern "C" void kernel_launch(void* const* d_in, const int* in_sizes, int n_in,
                              void* d_out, int out_size, void* d_ws, size_t ws_size,
                              hipStream_t stream) {
    const float* q_in = (const float*)d_in[0];
    const float* k_in = (const float*)d_in[1];
    const float* v_in = (const float*)d_in[2];
    const float* wq = (const float*)d_in[3];
    const float* bq = (const float*)d_in[4];
    const float* wk = (const float*)d_in[5];
    const float* wv = (const float*)d_in[7];
    const float* bv = (const float*)d_in[8];
    const float* wp = (const float*)d_in[9];
    const float* bp = (const float*)d_in[10];
    float* out = (float*)d_out;

    const size_t tensor_halves = (size_t)4 * NH * HW * DH;
    _Float16* Qhat = (_Float16*)d_ws;
    _Float16* Khat = Qhat + tensor_halves;
    _Float16* Vthat = Khat + tensor_halves;

    prepass_all<<<dim3(4096 + 1024), 256, 0, stream>>>(
        q_in, k_in, v_in, wq, bq, wk, wv, bv, Qhat, Khat, Vthat);
    attn_kernel<<<dim3(HW / QTILE, 4 * NH), 256, 0, stream>>>(
        Qhat, Khat, Vthat, wp, bp, out);
}